// Round 9
// baseline (190.918 us; speedup 1.0000x reference)
//
#include <hip/hip_runtime.h>
#include <hip/hip_bf16.h>

#define NROWS 8192
#define DIM 256
#define NT 64                     // 128-row tiles per matrix dim
#define TRI ((NT * (NT + 1)) / 2) // 2080 triangular tiles
#define NBLK (2 * TRI + NT * NT)  // 8256 total blocks

typedef __attribute__((ext_vector_type(8))) short short8;
typedef __attribute__((ext_vector_type(4))) float f32x4;

__device__ __forceinline__ ushort f2bf(float f) {
  unsigned u = __float_as_uint(f);
  u += 0x7fffu + ((u >> 16) & 1u);   // round-to-nearest-even
  return (ushort)(u >> 16);
}
__device__ __forceinline__ float bf2f(ushort b) {
  return __uint_as_float(((unsigned)b) << 16);
}

// exp(-0.5*d2) = exp2(C*d2), C = -0.5*log2(e); C folded into x2 at prep
#define NEGHALF_LOG2E (-0.72134752044448170368f)
#define LOG2E          (1.44269504088896340736f)

// ---- prep: f32 -> bf16 + row sum-of-squares of the bf16-rounded values.
__global__ __launch_bounds__(256) void prep_kernel(
    const float* __restrict__ S, const float* __restrict__ T,
    ushort* __restrict__ Sb, ushort* __restrict__ Tb,
    float* __restrict__ x2s, float* __restrict__ x2t,
    float* __restrict__ accums) {
  if (blockIdx.x == 0 && threadIdx.x == 0) accums[0] = 0.f;
  const int w = threadIdx.x >> 6, l = threadIdx.x & 63;
  const int r = blockIdx.x * 4 + w;
  const float* src;
  ushort* dst;
  float* sq;
  int row;
  if (r < NROWS) { src = S; dst = Sb; sq = x2s; row = r; }
  else           { src = T; dst = Tb; sq = x2t; row = r - NROWS; }

  const float4 v = *(const float4*)(src + (size_t)row * DIM + l * 4);
  float vf[4] = {v.x, v.y, v.z, v.w};
  ushort b[4];
  float s = 0.f;
#pragma unroll
  for (int i = 0; i < 4; ++i) {
    b[i] = f2bf(vf[i]);
    float f = bf2f(b[i]);
    s += f * f;
  }
  *(ushort4*)(dst + (size_t)row * DIM + l * 4) = make_ushort4(b[0], b[1], b[2], b[3]);
#pragma unroll
  for (int off = 32; off > 0; off >>= 1) s += __shfl_xor(s, off);
  if (l == 0) sq[row] = s * NEGHALF_LOG2E;
}

__device__ __forceinline__ void gload_lds16(const void* g, void* lds) {
  __builtin_amdgcn_global_load_lds(
      (const __attribute__((address_space(1))) unsigned int*)g,
      (__attribute__((address_space(3))) unsigned int*)lds, 16, 0, 0);
}

// ---- fused GEMM + exp2 + reduce. 128x128 tile, 4 waves, BK=32, double
// buffer, ~34 KB LDS -> 4 blocks/CU. Occupancy (TLP) hides stalls.
__global__ __launch_bounds__(256, 4) void mmd_gemm(
    const ushort* __restrict__ Sb, const ushort* __restrict__ Tb,
    const float* __restrict__ x2s, const float* __restrict__ x2t,
    float* __restrict__ accums) {
  // [buf][row*32 + k]; physical 16B-slot sp holds global slot sp^((row>>1)&3)
  __shared__ __align__(16) ushort lA[2][128 * 32];
  __shared__ __align__(16) ushort lB[2][128 * 32];
  __shared__ float lAx2[128];
  __shared__ float lBx2[128];
  __shared__ float wsum[4];

  const int tid = threadIdx.x;
  const int l = tid & 63;
  const int w = tid >> 6;
  const int wr = w >> 1, wc = w & 1;   // 2x2 waves; wave tile 64x64

  // ---- tile decode: [0,TRI) SS lower-tri, [TRI,2TRI) TT lower-tri, rest ST
  const int bid = blockIdx.x;
  const ushort* Ap;
  const ushort* Bp;
  const float* a2;
  const float* b2;
  int tr, tc;
  float wgt;
  if (bid < 2 * TRI) {
    const int i = (bid < TRI) ? bid : bid - TRI;
    int g = (int)((sqrtf((float)(8 * i + 1)) - 1.0f) * 0.5f);
    g = min(max(g - 2, 0), NT - 1);
    tr = g;
    while (tr < NT - 1 && (tr + 1) * (tr + 2) / 2 <= i) ++tr;
    tc = i - tr * (tr + 1) / 2;        // tr >= tc
    wgt = (tr == tc) ? 1.f : 2.f;
    if (bid < TRI) { Ap = Sb; Bp = Sb; a2 = x2s; b2 = x2s; }
    else           { Ap = Tb; Bp = Tb; a2 = x2t; b2 = x2t; }
  } else {
    const int t = bid - 2 * TRI;
    tr = t >> 6; tc = t & 63;
    wgt = -2.f;
    Ap = Sb; Bp = Tb; a2 = x2s; b2 = x2t;
  }

  const ushort* gA = Ap + (size_t)(tr * 128) * DIM;
  const ushort* gB = Bp + (size_t)(tc * 128) * DIM;

  // stage K-tile kt (128 rows x 4 slots of 16B, for A and B): dest lane-
  // linear, source slot pre-permuted so swizzled reads see logical k-order
#define STAGE(buf, kt)                                                     \
  {                                                                        \
    _Pragma("unroll")                                                      \
    for (int j = 0; j < 2; ++j) {                                          \
      const int c_ = j * 256 + tid;      /* chunk 0..511 */                \
      const int row_ = c_ >> 2, sp_ = c_ & 3;                              \
      const int sl_ = sp_ ^ ((row_ >> 1) & 3);                             \
      const size_t go_ = (size_t)row_ * DIM + (kt) * 32 + sl_ * 8;         \
      gload_lds16(gA + go_, &lA[buf][c_ * 8]);                             \
      gload_lds16(gB + go_, &lB[buf][c_ * 8]);                             \
    }                                                                      \
  }

  STAGE(0, 0);                          // tile 0 in flight

  // x2 rows into LDS while loads fly
  if (tid < 128) lAx2[tid] = a2[tr * 128 + tid];
  else           lBx2[tid - 128] = b2[tc * 128 + tid - 128];

  f32x4 acc[4][4];
  const f32x4 zero = {0.f, 0.f, 0.f, 0.f};
#pragma unroll
  for (int m = 0; m < 4; ++m)
#pragma unroll
    for (int n = 0; n < 4; ++n) acc[m][n] = zero;

#pragma unroll
  for (int kt = 0; kt < 8; ++kt) {
    const int cur = kt & 1;
    asm volatile("s_waitcnt vmcnt(0)" ::: "memory");  // tile kt in LDS
    __builtin_amdgcn_s_barrier();
    asm volatile("" ::: "memory");
    if (kt < 7) STAGE(cur ^ 1, kt + 1);  // next tile's 4 loads fly under MFMA

    short8 af[4], bfv[4];
#pragma unroll
    for (int m = 0; m < 4; ++m) {
      const int row = wr * 64 + m * 16 + (l & 15);
      const int sp = (l >> 4) ^ ((row >> 1) & 3);
      af[m] = *(const short8*)&lA[cur][row * 32 + sp * 8];
    }
#pragma unroll
    for (int n = 0; n < 4; ++n) {
      const int row = wc * 64 + n * 16 + (l & 15);
      const int sp = (l >> 4) ^ ((row >> 1) & 3);
      bfv[n] = *(const short8*)&lB[cur][row * 32 + sp * 8];
    }
    __builtin_amdgcn_s_setprio(1);
#pragma unroll
    for (int m = 0; m < 4; ++m)
#pragma unroll
      for (int n = 0; n < 4; ++n)
        acc[m][n] = __builtin_amdgcn_mfma_f32_16x16x32_bf16(af[m], bfv[n], acc[m][n], 0, 0, 0);
    __builtin_amdgcn_s_setprio(0);
    asm volatile("" ::: "memory");
    __builtin_amdgcn_s_barrier();       // buf[cur] consumed; reusable next+1
  }

  // ---- fused epilogue: arg = C*(x2_i + x2_j) + log2e*dot, clamp <=0, exp2
  float cb[4];
#pragma unroll
  for (int n = 0; n < 4; ++n) cb[n] = lBx2[wc * 64 + n * 16 + (l & 15)];
  float local = 0.f;
#pragma unroll
  for (int m = 0; m < 4; ++m) {
#pragma unroll
    for (int j = 0; j < 4; ++j) {
      const float rc = lAx2[wr * 64 + m * 16 + ((l >> 4) * 4 + j)];
#pragma unroll
      for (int n = 0; n < 4; ++n) {
        float arg = fmaf(LOG2E, acc[m][n][j], rc + cb[n]);
        arg = fminf(arg, 0.f);
        local += exp2f(arg);
      }
    }
  }
#pragma unroll
  for (int off = 32; off > 0; off >>= 1) local += __shfl_xor(local, off);
  if (l == 0) wsum[w] = local;
  __syncthreads();
  if (tid == 0) {
    atomicAdd(&accums[0], (wsum[0] + wsum[1] + wsum[2] + wsum[3]) * wgt);
  }
}

__global__ void finalize_kernel(const float* __restrict__ accums, float* __restrict__ out) {
  out[0] = accums[0] * (1.f / ((float)NROWS * (float)NROWS));
}

extern "C" void kernel_launch(void* const* d_in, const int* in_sizes, int n_in,
                              void* d_out, int out_size, void* d_ws, size_t ws_size,
                              hipStream_t stream) {
  const float* S = (const float*)d_in[0];
  const float* T = (const float*)d_in[1];
  float* out = (float*)d_out;

  ushort* Sb = (ushort*)d_ws;                      // 4 MB
  ushort* Tb = Sb + (size_t)NROWS * DIM;           // 4 MB
  float* x2s = (float*)(Tb + (size_t)NROWS * DIM); // 32 KB
  float* x2t = x2s + NROWS;                        // 32 KB
  float* accums = x2t + NROWS;                     // [0]=sum

  prep_kernel<<<(2 * NROWS) / 4, 256, 0, stream>>>(S, T, Sb, Tb, x2s, x2t, accums);
  mmd_gemm<<<NBLK, 256, 0, stream>>>(Sb, Tb, x2s, x2t, accums);
  finalize_kernel<<<1, 1, 0, stream>>>(accums, out);
}

// Round 11
// 190.573 us; speedup vs baseline: 1.0018x; 1.0018x over previous
//
#include <hip/hip_runtime.h>

#define NROWS 8192
#define DIM 256
#define NT 64                     // 128-row tiles per matrix dim
#define TRI ((NT * (NT + 1)) / 2) // 2080 triangular tiles
#define NBLK (2 * TRI + NT * NT)  // 8256 total blocks

typedef __attribute__((ext_vector_type(4))) float f32x4;

// exp(-0.5*d2) = exp2(C*d2), C = -0.5*log2(e); C folded into x2 at prep
#define NEGHALF_LOG2E (-0.72134752044448170368f)
#define LOG2E          (1.44269504088896340736f)

// ---- prep: f32 -> fp8 e4m3 (OCP) + row sum-of-squares of the fp8-rounded
// values (so the SS/TT diagonal d2 is ~0 exactly). 4 elems/thread.
__global__ __launch_bounds__(256) void prep_kernel(
    const float* __restrict__ S, const float* __restrict__ T,
    unsigned* __restrict__ Sb, unsigned* __restrict__ Tb,  // fp8 as packed uints
    float* __restrict__ x2s, float* __restrict__ x2t,
    float* __restrict__ accums) {
  if (blockIdx.x == 0 && threadIdx.x == 0) accums[0] = 0.f;
  const int w = threadIdx.x >> 6, l = threadIdx.x & 63;
  const int r = blockIdx.x * 4 + w;
  const float* src;
  unsigned* dst;
  float* sq;
  int row;
  if (r < NROWS) { src = S; dst = Sb; sq = x2s; row = r; }
  else           { src = T; dst = Tb; sq = x2t; row = r - NROWS; }

  const float4 v = *(const float4*)(src + (size_t)row * DIM + l * 4);
  int packed = __builtin_amdgcn_cvt_pk_fp8_f32(v.x, v.y, 0, false);      // lo word
  packed = __builtin_amdgcn_cvt_pk_fp8_f32(v.z, v.w, packed, true);      // hi word
  const float d0 = __builtin_amdgcn_cvt_f32_fp8(packed, 0);
  const float d1 = __builtin_amdgcn_cvt_f32_fp8(packed, 1);
  const float d2 = __builtin_amdgcn_cvt_f32_fp8(packed, 2);
  const float d3 = __builtin_amdgcn_cvt_f32_fp8(packed, 3);
  float s = d0 * d0 + d1 * d1 + d2 * d2 + d3 * d3;
  dst[(size_t)row * (DIM / 4) + l] = (unsigned)packed;   // 4 fp8 per uint
#pragma unroll
  for (int off = 32; off > 0; off >>= 1) s += __shfl_xor(s, off);
  if (l == 0) sq[row] = s * NEGHALF_LOG2E;
}

__device__ __forceinline__ void gload_lds16(const void* g, void* lds) {
  __builtin_amdgcn_global_load_lds(
      (const __attribute__((address_space(1))) unsigned int*)g,
      (__attribute__((address_space(3))) unsigned int*)lds, 16, 0, 0);
}

// ---- fused GEMM + exp2 + reduce. 128x128 tile, 4 waves, BK=32 in fp8,
// double buffer. LDS ~17 KB; fp8 halves LDS pipe traffic (the measured
// bottleneck): frags are ds_read_b64 (4-lane/bank = wave floor, no swizzle).
__global__ __launch_bounds__(256, 4) void mmd_gemm(
    const unsigned char* __restrict__ Sb, const unsigned char* __restrict__ Tb,
    const float* __restrict__ x2s, const float* __restrict__ x2t,
    float* __restrict__ accums) {
  __shared__ __align__(16) unsigned char lA[2][128 * 32];  // [buf][row*32+k] fp8, linear
  __shared__ __align__(16) unsigned char lB[2][128 * 32];
  __shared__ float lAx2[128];
  __shared__ float lBx2[128];
  __shared__ float wsum[4];

  const int tid = threadIdx.x;
  const int l = tid & 63;
  const int w = tid >> 6;
  const int wr = w >> 1, wc = w & 1;   // 2x2 waves; wave tile 64x64

  // ---- tile decode: [0,TRI) SS lower-tri, [TRI,2TRI) TT lower-tri, rest ST
  const int bid = blockIdx.x;
  const unsigned char* Ap;
  const unsigned char* Bp;
  const float* a2;
  const float* b2;
  int tr, tc;
  float wgt;
  if (bid < 2 * TRI) {
    const int i = (bid < TRI) ? bid : bid - TRI;
    int g = (int)((sqrtf((float)(8 * i + 1)) - 1.0f) * 0.5f);
    g = min(max(g - 2, 0), NT - 1);
    tr = g;
    while (tr < NT - 1 && (tr + 1) * (tr + 2) / 2 <= i) ++tr;
    tc = i - tr * (tr + 1) / 2;        // tr >= tc
    wgt = (tr == tc) ? 1.f : 2.f;
    if (bid < TRI) { Ap = Sb; Bp = Sb; a2 = x2s; b2 = x2s; }
    else           { Ap = Tb; Bp = Tb; a2 = x2t; b2 = x2t; }
  } else {
    const int t = bid - 2 * TRI;
    tr = t >> 6; tc = t & 63;
    wgt = -2.f;
    Ap = Sb; Bp = Tb; a2 = x2s; b2 = x2t;
  }

  const unsigned char* gA = Ap + (size_t)(tr * 128) * DIM;
  const unsigned char* gB = Bp + (size_t)(tc * 128) * DIM;

  // stage K-tile kt: 128 rows x 32 fp8 = 4 KB/operand = 256 16B-chunks,
  // exactly one chunk per thread per operand; dest lane-linear, source linear.
#define STAGE(buf, kt)                                                     \
  {                                                                        \
    const int row_ = tid >> 1, o_ = tid & 1;                               \
    const size_t go_ = (size_t)row_ * DIM + (kt) * 32 + o_ * 16;           \
    gload_lds16(gA + go_, &lA[buf][tid * 16]);                             \
    gload_lds16(gB + go_, &lB[buf][tid * 16]);                             \
  }

  STAGE(0, 0);                          // tile 0 in flight

  // x2 rows into LDS while loads fly
  if (tid < 128) lAx2[tid] = a2[tr * 128 + tid];
  else           lBx2[tid - 128] = b2[tc * 128 + tid - 128];

  f32x4 acc[4][4];
  const f32x4 zero = {0.f, 0.f, 0.f, 0.f};
#pragma unroll
  for (int m = 0; m < 4; ++m)
#pragma unroll
    for (int n = 0; n < 4; ++n) acc[m][n] = zero;

#pragma unroll
  for (int kt = 0; kt < 8; ++kt) {
    const int cur = kt & 1;
    asm volatile("s_waitcnt vmcnt(0)" ::: "memory");  // tile kt in LDS
    __builtin_amdgcn_s_barrier();
    asm volatile("" ::: "memory");
    if (kt < 7) STAGE(cur ^ 1, kt + 1);  // next tile's 2 loads fly under MFMA

    long af[4], bfv[4];
#pragma unroll
    for (int m = 0; m < 4; ++m) {
      const int row = wr * 64 + m * 16 + (l & 15);
      af[m] = *(const long*)&lA[cur][row * 32 + (l >> 4) * 8];
    }
#pragma unroll
    for (int n = 0; n < 4; ++n) {
      const int row = wc * 64 + n * 16 + (l & 15);
      bfv[n] = *(const long*)&lB[cur][row * 32 + (l >> 4) * 8];
    }
    __builtin_amdgcn_s_setprio(1);
#pragma unroll
    for (int m = 0; m < 4; ++m)
#pragma unroll
      for (int n = 0; n < 4; ++n)
        acc[m][n] = __builtin_amdgcn_mfma_f32_16x16x32_fp8_fp8(af[m], bfv[n], acc[m][n], 0, 0, 0);
    __builtin_amdgcn_s_setprio(0);
    asm volatile("" ::: "memory");
    __builtin_amdgcn_s_barrier();       // buf[cur] consumed; reusable next+1
  }

  // ---- fused epilogue: arg = C*(x2_i + x2_j) + log2e*dot, clamp <=0, exp2
  float cb[4];
#pragma unroll
  for (int n = 0; n < 4; ++n) cb[n] = lBx2[wc * 64 + n * 16 + (l & 15)];
  float local = 0.f;
#pragma unroll
  for (int m = 0; m < 4; ++m) {
#pragma unroll
    for (int j = 0; j < 4; ++j) {
      const float rc = lAx2[wr * 64 + m * 16 + ((l >> 4) * 4 + j)];
#pragma unroll
      for (int n = 0; n < 4; ++n) {
        float arg = fmaf(LOG2E, acc[m][n][j], rc + cb[n]);
        arg = fminf(arg, 0.f);
        local += exp2f(arg);
      }
    }
  }
#pragma unroll
  for (int off = 32; off > 0; off >>= 1) local += __shfl_xor(local, off);
  if (l == 0) wsum[w] = local;
  __syncthreads();
  if (tid == 0) {
    atomicAdd(&accums[0], (wsum[0] + wsum[1] + wsum[2] + wsum[3]) * wgt);
  }
}

__global__ void finalize_kernel(const float* __restrict__ accums, float* __restrict__ out) {
  out[0] = accums[0] * (1.f / ((float)NROWS * (float)NROWS));
}

extern "C" void kernel_launch(void* const* d_in, const int* in_sizes, int n_in,
                              void* d_out, int out_size, void* d_ws, size_t ws_size,
                              hipStream_t stream) {
  const float* S = (const float*)d_in[0];
  const float* T = (const float*)d_in[1];
  float* out = (float*)d_out;

  unsigned char* Sb = (unsigned char*)d_ws;            // 2 MB fp8
  unsigned char* Tb = Sb + (size_t)NROWS * DIM;        // 2 MB fp8
  float* x2s = (float*)(Tb + (size_t)NROWS * DIM);     // 32 KB
  float* x2t = x2s + NROWS;                            // 32 KB
  float* accums = x2t + NROWS;                         // [0]=sum

  prep_kernel<<<(2 * NROWS) / 4, 256, 0, stream>>>(S, T, (unsigned*)Sb, (unsigned*)Tb,
                                                   x2s, x2t, accums);
  mmd_gemm<<<NBLK, 256, 0, stream>>>(Sb, Tb, x2s, x2t, accums);
  finalize_kernel<<<1, 1, 0, stream>>>(accums, out);
}

// Round 12
// 184.371 us; speedup vs baseline: 1.0355x; 1.0336x over previous
//
#include <hip/hip_runtime.h>

#define NROWS 8192
#define DIM 256
#define NT 64                     // 128-row tiles per matrix dim
#define TRI ((NT * (NT + 1)) / 2) // 2080 triangular tiles
#define NBLK (2 * TRI + NT * NT)  // 8256 total blocks

typedef __attribute__((ext_vector_type(4))) float f32x4;
typedef __attribute__((ext_vector_type(2))) long long2v;

// exp(-0.5*d2) = exp2(C*d2), C = -0.5*log2(e); C folded into x2 at prep
#define NEGHALF_LOG2E (-0.72134752044448170368f)
#define LOG2E          (1.44269504088896340736f)

// Fragment-major fp8 layout, per 16-row panel (4096 B):
//   byte(row, k) -> off = panel*4096 + (k>>6)*1024 + (((k>>3)&3)*16 + (row&15))*16
//                         + ((k>>5)&1)*8 + (k&7)
// so a 16x16x32-MFMA A/B fragment for (panel, kt) is the contiguous 1 KB at
// panel*4096 + (kt>>1)*1024, lane-ordered: lane l takes bytes l*16 + (kt&1)*8.
__global__ __launch_bounds__(256) void prep_kernel(
    const float* __restrict__ S, const float* __restrict__ T,
    unsigned char* __restrict__ Sb, unsigned char* __restrict__ Tb,
    float* __restrict__ x2s, float* __restrict__ x2t,
    float* __restrict__ accums) {
  __shared__ unsigned char lds8[4][16][264];   // +8B row pad: conflict-free
  if (blockIdx.x == 0 && threadIdx.x == 0) accums[0] = 0.f;
  const int w = threadIdx.x >> 6, l = threadIdx.x & 63;
  const int pg = blockIdx.x * 4 + w;           // global panel 0..1023
  const float* src;
  unsigned char* dst;
  float* sq;
  int p;
  if (pg < 512) { src = S; dst = Sb; sq = x2s; p = pg; }
  else          { src = T; dst = Tb; sq = x2t; p = pg - 512; }
  const int r0 = p * 16;

  // phase 1: coalesced f32 row reads -> fp8 -> LDS; per-row x2 of the
  // fp8-rounded values (keeps the SS/TT diagonal d2 ~ 0)
  for (int r = 0; r < 16; ++r) {
    const float4 v = *(const float4*)(src + (size_t)(r0 + r) * DIM + l * 4);
    int pk = __builtin_amdgcn_cvt_pk_fp8_f32(v.x, v.y, 0, false);
    pk = __builtin_amdgcn_cvt_pk_fp8_f32(v.z, v.w, pk, true);
    *(unsigned*)&lds8[w][r][l * 4] = (unsigned)pk;
    const float d0 = __builtin_amdgcn_cvt_f32_fp8(pk, 0);
    const float d1 = __builtin_amdgcn_cvt_f32_fp8(pk, 1);
    const float d2 = __builtin_amdgcn_cvt_f32_fp8(pk, 2);
    const float d3 = __builtin_amdgcn_cvt_f32_fp8(pk, 3);
    float s = d0 * d0 + d1 * d1 + d2 * d2 + d3 * d3;
#pragma unroll
    for (int off = 32; off > 0; off >>= 1) s += __shfl_xor(s, off);
    if (l == 0) sq[r0 + r] = s * NEGHALF_LOG2E;
  }
  __syncthreads();

  // phase 2: emit fragment-major, 4 x dwordx4 per lane, fully coalesced
  const int rr = l & 15, ss = l >> 4;
#pragma unroll
  for (int j = 0; j < 4; ++j) {
    long2v o;
    o[0] = *(const long*)&lds8[w][rr][(2 * j + 0) * 32 + ss * 8];
    o[1] = *(const long*)&lds8[w][rr][(2 * j + 1) * 32 + ss * 8];
    *(long2v*)(dst + (size_t)p * 4096 + j * 1024 + l * 16) = o;
  }
}

// ---- fused GEMM + exp2 + reduce. 128x128 tile, 4 waves, NO LDS staging:
// fragment loads go global->VGPR (1 KB coalesced per inst), register
// double-buffer, zero barriers in the K-loop. L2-resident operands.
__global__ __launch_bounds__(256, 3) void mmd_gemm(
    const unsigned char* __restrict__ Sb, const unsigned char* __restrict__ Tb,
    const float* __restrict__ x2s, const float* __restrict__ x2t,
    float* __restrict__ accums) {
  __shared__ float wsum[4];

  const int tid = threadIdx.x;
  const int l = tid & 63;
  const int w = tid >> 6;
  const int wr = w >> 1, wc = w & 1;   // 2x2 waves; wave tile 64x64

  // ---- tile decode: [0,TRI) SS lower-tri, [TRI,2TRI) TT lower-tri, rest ST
  const int bid = blockIdx.x;
  const unsigned char* Ap;
  const unsigned char* Bp;
  const float* a2;
  const float* b2;
  int tr, tc;
  float wgt;
  if (bid < 2 * TRI) {
    const int i = (bid < TRI) ? bid : bid - TRI;
    int g = (int)((sqrtf((float)(8 * i + 1)) - 1.0f) * 0.5f);
    g = min(max(g - 2, 0), NT - 1);
    tr = g;
    while (tr < NT - 1 && (tr + 1) * (tr + 2) / 2 <= i) ++tr;
    tc = i - tr * (tr + 1) / 2;        // tr >= tc
    wgt = (tr == tc) ? 1.f : 2.f;
    if (bid < TRI) { Ap = Sb; Bp = Sb; a2 = x2s; b2 = x2s; }
    else           { Ap = Tb; Bp = Tb; a2 = x2t; b2 = x2t; }
  } else {
    const int t = bid - 2 * TRI;
    tr = t >> 6; tc = t & 63;
    wgt = -2.f;
    Ap = Sb; Bp = Tb; a2 = x2s; b2 = x2t;
  }

  // fragment base pointers (panel = 16 rows; 128-row tile = 8 panels)
  const unsigned char* pA = Ap + ((size_t)(tr * 8 + wr * 4)) * 4096 + l * 16;
  const unsigned char* pB = Bp + ((size_t)(tc * 8 + wc * 4)) * 4096 + l * 16;

  f32x4 acc[4][4];
  const f32x4 zero = {0.f, 0.f, 0.f, 0.f};
#pragma unroll
  for (int m = 0; m < 4; ++m)
#pragma unroll
    for (int n = 0; n < 4; ++n) acc[m][n] = zero;

  long2v a4[2][4], b4[2][4];
#define LOADP(buf, pr)                                                   \
  {                                                                      \
    _Pragma("unroll")                                                    \
    for (int m = 0; m < 4; ++m) {                                        \
      a4[buf][m] = *(const long2v*)(pA + m * 4096 + (pr) * 1024);        \
      b4[buf][m] = *(const long2v*)(pB + m * 4096 + (pr) * 1024);        \
    }                                                                    \
  }

  LOADP(0, 0);
#pragma unroll
  for (int pr = 0; pr < 4; ++pr) {      // K-pair = 64 wide, 8 kt total
    const int cur = pr & 1;
    if (pr < 3) LOADP(cur ^ 1, pr + 1); // next pair flies under 32 MFMA
#pragma unroll
    for (int h = 0; h < 2; ++h)
#pragma unroll
      for (int m = 0; m < 4; ++m)
#pragma unroll
        for (int n = 0; n < 4; ++n)
          acc[m][n] = __builtin_amdgcn_mfma_f32_16x16x32_fp8_fp8(
              a4[cur][m][h], b4[cur][n][h], acc[m][n], 0, 0, 0);
  }

  // ---- fused epilogue: arg = C*(x2_i + x2_j) + log2e*dot; x2 from global
  float cb[4];
#pragma unroll
  for (int n = 0; n < 4; ++n)
    cb[n] = b2[tc * 128 + wc * 64 + n * 16 + (l & 15)];
  float local = 0.f;
#pragma unroll
  for (int m = 0; m < 4; ++m) {
#pragma unroll
    for (int j = 0; j < 4; ++j) {
      const float rc = a2[tr * 128 + wr * 64 + m * 16 + (l >> 4) * 4 + j];
#pragma unroll
      for (int n = 0; n < 4; ++n) {
        float arg = fmaf(LOG2E, acc[m][n][j], rc + cb[n]);
        arg = fminf(arg, 0.f);
        local += exp2f(arg);
      }
    }
  }
#pragma unroll
  for (int off = 32; off > 0; off >>= 1) local += __shfl_xor(local, off);
  if (l == 0) wsum[w] = local;
  __syncthreads();
  if (tid == 0) {
    atomicAdd(&accums[0], (wsum[0] + wsum[1] + wsum[2] + wsum[3]) * wgt);
  }
}

__global__ void finalize_kernel(const float* __restrict__ accums, float* __restrict__ out) {
  out[0] = accums[0] * (1.f / ((float)NROWS * (float)NROWS));
}

extern "C" void kernel_launch(void* const* d_in, const int* in_sizes, int n_in,
                              void* d_out, int out_size, void* d_ws, size_t ws_size,
                              hipStream_t stream) {
  const float* S = (const float*)d_in[0];
  const float* T = (const float*)d_in[1];
  float* out = (float*)d_out;

  unsigned char* Sb = (unsigned char*)d_ws;            // 2 MB fp8, fragment-major
  unsigned char* Tb = Sb + (size_t)NROWS * DIM;        // 2 MB
  float* x2s = (float*)(Tb + (size_t)NROWS * DIM);     // 32 KB
  float* x2t = x2s + NROWS;                            // 32 KB
  float* accums = x2t + NROWS;                         // [0]=sum

  prep_kernel<<<(2 * NROWS / 16) / 4, 256, 0, stream>>>(S, T, Sb, Tb, x2s, x2t, accums);
  mmd_gemm<<<NBLK, 256, 0, stream>>>(Sb, Tb, x2s, x2t, accums);
  finalize_kernel<<<1, 1, 0, stream>>>(accums, out);
}